// Round 8
// baseline (284.451 us; speedup 1.0000x reference)
//
#include <hip/hip_runtime.h>

// ---------------------------------------------------------------------------
// 3-layer GraphSAGE (mean aggregation) + final linear.
// N=50000, 128 ch hidden, 800000 edges, out 16.
// R4: split-bf16 (hi/lo) MFMA GEMMs, K=256 combined; CSR de-atomic'd fill.
// R5/R6 (REGRESSED, reverted): shfl-heavy agg / channel-sliced agg.
// R7: aggregate unroll-8 (276us).
// R8: aggregate unroll-16 (one miss round at avg deg 16);
//     GEMM re-tiled 64x128, 2 waves, 782 blocks = 3.05/CU (load balance;
//     391 blocks @ 1.53/CU had a 2x tail).
// ---------------------------------------------------------------------------

typedef short bf16x8 __attribute__((ext_vector_type(8)));  // 8 bf16 (4 VGPRs)
typedef float f32x4 __attribute__((ext_vector_type(4)));

__device__ __forceinline__ float bf16_to_f32(unsigned int lo16) {
  unsigned int u = lo16 << 16;
  return __builtin_bit_cast(float, u);
}
__device__ __forceinline__ unsigned short f32_to_bf16(float f) {
  unsigned int u = __builtin_bit_cast(unsigned int, f);
  unsigned int r = (u + 0x7FFFu + ((u >> 16) & 1u)) >> 16;  // RNE
  return (unsigned short)r;
}

// async global->LDS, 16B per lane; lds base must be wave-uniform.
__device__ __forceinline__ void gload_lds16(void* g, void* lds_base) {
  __builtin_amdgcn_global_load_lds(
      (__attribute__((address_space(1))) unsigned int*)(uintptr_t)g,
      (__attribute__((address_space(3))) unsigned int*)(unsigned int)(uintptr_t)lds_base,
      16, 0, 0);
}

__global__ void k_zero_i32(int* __restrict__ p, int n) {
  int i = blockIdx.x * blockDim.x + threadIdx.x;
  if (i < n) p[i] = 0;
}

// fp32 -> bf16 hi/lo split, 4 elems/thread
__global__ __launch_bounds__(256) void k_split(const float* __restrict__ in,
                                               unsigned short* __restrict__ hi,
                                               unsigned short* __restrict__ lo, int n4) {
  int i = blockIdx.x * blockDim.x + threadIdx.x;
  if (i < n4) {
    float4 v = *reinterpret_cast<const float4*>(&in[(size_t)i * 4]);
    ushort4 h, l;
    h.x = f32_to_bf16(v.x); l.x = f32_to_bf16(v.x - bf16_to_f32(h.x));
    h.y = f32_to_bf16(v.y); l.y = f32_to_bf16(v.y - bf16_to_f32(h.y));
    h.z = f32_to_bf16(v.z); l.z = f32_to_bf16(v.z - bf16_to_f32(h.z));
    h.w = f32_to_bf16(v.w); l.w = f32_to_bf16(v.w - bf16_to_f32(h.w));
    *reinterpret_cast<ushort4*>(&hi[(size_t)i * 4]) = h;
    *reinterpret_cast<ushort4*>(&lo[(size_t)i * 4]) = l;
  }
}

// Weights: Wt[n][k] = (k<128 ? Wl[k][n] : Wr[k-128][n]), split hi/lo.
__global__ __launch_bounds__(256) void k_prep_w(const float* __restrict__ Wl,
                                                const float* __restrict__ Wr,
                                                unsigned short* __restrict__ Whi,
                                                unsigned short* __restrict__ Wlo) {
  int n = blockIdx.x, k = threadIdx.x;  // 128 blocks x 256 threads
  float v = (k < 128) ? Wl[(size_t)k * 128 + n] : Wr[(size_t)(k - 128) * 128 + n];
  unsigned short h = f32_to_bf16(v);
  Whi[(size_t)n * 256 + k] = h;
  Wlo[(size_t)n * 256 + k] = f32_to_bf16(v - bf16_to_f32(h));
}

// int32-vs-int64 edge_index detection
__global__ void k_detect(const int* __restrict__ ei, int* __restrict__ flag) {
  int t = threadIdx.x;
  int any = 0;
  for (int i = t; i < 1024; i += 256)
    if (ei[2 * i + 1] != 0) any = 1;
  if (any) atomicOr(flag, 1);
}

__device__ __forceinline__ int load_src(const int* ei, int E, int i, int is32) {
  return is32 ? ei[i] : ei[2 * i];
}
__device__ __forceinline__ int load_dst(const int* ei, int E, int i, int is32) {
  return is32 ? ei[E + i] : ei[2 * E + 2 * i];
}

// count degree + capture per-edge rank (removes atomic from k_fill)
__global__ __launch_bounds__(256) void k_count(const int* __restrict__ ei,
                                               const int* __restrict__ flag,
                                               int* __restrict__ deg,
                                               int* __restrict__ erank, int E) {
  int i = blockIdx.x * blockDim.x + threadIdx.x;
  if (i < E) {
    int is32 = *flag;
    erank[i] = atomicAdd(&deg[load_dst(ei, E, i, is32)], 1);
  }
}

// --- device-wide exclusive scan over deg (3 passes, 1024 elems/block) ------
__global__ __launch_bounds__(256) void k_scan1(const int* __restrict__ deg,
                                               int* __restrict__ bsum, int N) {
  __shared__ int s[256];
  int t = threadIdx.x;
  int base = blockIdx.x * 1024 + t * 4;
  int v = 0;
#pragma unroll
  for (int j = 0; j < 4; ++j) {
    int i = base + j;
    v += (i < N) ? deg[i] : 0;
  }
  s[t] = v;
  __syncthreads();
  for (int off = 128; off > 0; off >>= 1) {
    if (t < off) s[t] += s[t + off];
    __syncthreads();
  }
  if (t == 0) bsum[blockIdx.x] = s[0];
}

__global__ __launch_bounds__(1024) void k_scan2(int* __restrict__ bsum,
                                                int* __restrict__ row_ptr,
                                                int nb, int N) {
  __shared__ int s[1024];
  int t = threadIdx.x;
  int v = (t < nb) ? bsum[t] : 0;
  s[t] = v;
  __syncthreads();
  for (int off = 1; off < 1024; off <<= 1) {
    int add = (t >= off) ? s[t - off] : 0;
    __syncthreads();
    s[t] += add;
    __syncthreads();
  }
  if (t < nb) bsum[t] = s[t] - v;  // exclusive
  if (t == 1023) row_ptr[N] = s[1023];
}

__global__ __launch_bounds__(256) void k_scan3(const int* __restrict__ deg,
                                               const int* __restrict__ bsum,
                                               int* __restrict__ row_ptr,
                                               float* __restrict__ inv_deg, int N) {
  __shared__ int s[256];
  int t = threadIdx.x;
  int base = blockIdx.x * 1024 + t * 4;
  int v[4];
  int sum = 0;
#pragma unroll
  for (int j = 0; j < 4; ++j) {
    int i = base + j;
    v[j] = (i < N) ? deg[i] : 0;
    sum += v[j];
  }
  s[t] = sum;
  __syncthreads();
  for (int off = 1; off < 256; off <<= 1) {
    int add = (t >= off) ? s[t - off] : 0;
    __syncthreads();
    s[t] += add;
    __syncthreads();
  }
  int excl = s[t] - sum + bsum[blockIdx.x];
#pragma unroll
  for (int j = 0; j < 4; ++j) {
    int i = base + j;
    if (i < N) {
      row_ptr[i] = excl;
      inv_deg[i] = 1.0f / (float)((v[j] > 1) ? v[j] : 1);
      excl += v[j];
    }
  }
}

// pure scatter fill (rank precomputed)
__global__ __launch_bounds__(256) void k_fill(const int* __restrict__ ei,
                                              const int* __restrict__ flag,
                                              const int* __restrict__ row_ptr,
                                              const int* __restrict__ erank,
                                              int* __restrict__ col_idx, int E) {
  int i = blockIdx.x * blockDim.x + threadIdx.x;
  if (i < E) {
    int is32 = *flag;
    int d = load_dst(ei, E, i, is32);
    int s = load_src(ei, E, i, is32);
    col_idx[row_ptr[d] + erank[i]] = s;
  }
}

// One wave per node, 4B/lane = full 256B row per load, unroll-16 (16 gathers
// in flight; paired accumulation into 8 slots caps VGPR). No shuffles/LDS.
__global__ __launch_bounds__(256) void k_aggregate(const unsigned short* __restrict__ Xhi,
                                                   const int* __restrict__ row_ptr,
                                                   const int* __restrict__ col_idx,
                                                   const float* __restrict__ inv_deg,
                                                   unsigned int* __restrict__ Mhi,
                                                   unsigned int* __restrict__ Mlo, int N) {
  int gw = (int)((blockIdx.x * blockDim.x + threadIdx.x) >> 6);
  int lane = threadIdx.x & 63;
  if (gw >= N) return;
  int s = row_ptr[gw], e = row_ptr[gw + 1];
  const unsigned int* Xp =
      reinterpret_cast<const unsigned int*>(Xhi) + lane;  // row stride 64 u32
  float ax[8], ay[8];
#pragma unroll
  for (int q = 0; q < 8; ++q) { ax[q] = 0.f; ay[q] = 0.f; }
  int j = s;
  for (; j + 16 <= e; j += 16) {
    unsigned int v[16];
#pragma unroll
    for (int q = 0; q < 16; ++q) v[q] = Xp[(size_t)col_idx[j + q] * 64];
#pragma unroll
    for (int q = 0; q < 16; ++q) {
      ax[q & 7] += bf16_to_f32(v[q] & 0xFFFFu);
      ay[q & 7] += bf16_to_f32(v[q] >> 16);
    }
  }
  for (; j + 8 <= e; j += 8) {
    unsigned int v[8];
#pragma unroll
    for (int q = 0; q < 8; ++q) v[q] = Xp[(size_t)col_idx[j + q] * 64];
#pragma unroll
    for (int q = 0; q < 8; ++q) {
      ax[q] += bf16_to_f32(v[q] & 0xFFFFu);
      ay[q] += bf16_to_f32(v[q] >> 16);
    }
  }
  for (; j + 4 <= e; j += 4) {
    unsigned int v[4];
#pragma unroll
    for (int q = 0; q < 4; ++q) v[q] = Xp[(size_t)col_idx[j + q] * 64];
#pragma unroll
    for (int q = 0; q < 4; ++q) {
      ax[q] += bf16_to_f32(v[q] & 0xFFFFu);
      ay[q] += bf16_to_f32(v[q] >> 16);
    }
  }
  for (; j < e; ++j) {
    unsigned int v = Xp[(size_t)col_idx[j] * 64];
    ax[0] += bf16_to_f32(v & 0xFFFFu);
    ay[0] += bf16_to_f32(v >> 16);
  }
  float inv = inv_deg[gw];
  float rx = ((ax[0] + ax[1]) + (ax[2] + ax[3])) + ((ax[4] + ax[5]) + (ax[6] + ax[7]));
  float ry = ((ay[0] + ay[1]) + (ay[2] + ay[3])) + ((ay[4] + ay[5]) + (ay[6] + ay[7]));
  rx *= inv;
  ry *= inv;
  unsigned int hx = f32_to_bf16(rx), hy = f32_to_bf16(ry);
  unsigned int lx = f32_to_bf16(rx - bf16_to_f32(hx));
  unsigned int ly = f32_to_bf16(ry - bf16_to_f32(hy));
  Mhi[(size_t)gw * 64 + lane] = hx | (hy << 16);
  Mlo[(size_t)gw * 64 + lane] = lx | (ly << 16);
}

// MFMA GEMM: Out = relu([A1 | A2](N x 256) @ Wt^T + bias), split-bf16 3-pass.
// Block: 64 rows x 128 cols, 2 waves (cols split), wave = 64x64 via 4x4
// 16x16x32 MFMA. 782 blocks = 3.05/CU (balanced). Wave0 stages hi, wave1 lo.
__global__ __launch_bounds__(128) void k_mfma_gemm(
    const unsigned short* __restrict__ A1hi, const unsigned short* __restrict__ A1lo,
    const unsigned short* __restrict__ A2hi, const unsigned short* __restrict__ A2lo,
    const unsigned short* __restrict__ Whi, const unsigned short* __restrict__ Wlo,
    const float* __restrict__ bias,
    unsigned short* __restrict__ Ohi, unsigned short* __restrict__ Olo, int N) {
  __shared__ unsigned short sAhi[64 * 32], sAlo[64 * 32];    // 4KB each
  __shared__ unsigned short sBhi[128 * 32], sBlo[128 * 32];  // 8KB each
  int t = threadIdx.x;
  int lane = t & 63;
  int w = t >> 6;   // 0: hi stager, 1: lo stager
  int wc = w * 64;  // output col offset of this wave
  int block_row = blockIdx.x * 64;

  f32x4 acc[4][4];
#pragma unroll
  for (int m = 0; m < 4; ++m)
#pragma unroll
    for (int n = 0; n < 4; ++n) acc[m][n] = f32x4{0.f, 0.f, 0.f, 0.f};

  int kg = lane & 3;           // 16B group within 64B row
  int rr = lane >> 2;          // 0..15 row-within-chunk
  int fr = lane & 15;          // fragment row/col
  int fkb = (lane >> 4) * 16;  // fragment k byte offset

  for (int kt = 0; kt < 8; ++kt) {
    {
      const unsigned short* gA = (w == 0) ? ((kt < 4) ? A1hi : A2hi)
                                          : ((kt < 4) ? A1lo : A2lo);
      const unsigned short* gB = (w == 0) ? Whi : Wlo;
      unsigned short* lA = (w == 0) ? sAhi : sAlo;
      unsigned short* lB = (w == 0) ? sBhi : sBlo;
#pragma unroll
      for (int c = 0; c < 4; ++c) {  // A: 64 rows x 64B
        int idx = c * 16 + rr;
        int rg = block_row + idx;
        if (rg > N - 1) rg = N - 1;
        const char* src = (const char*)gA + (size_t)rg * 256 + (kt & 3) * 64 + kg * 16;
        gload_lds16((void*)src, (char*)lA + c * 1024);
      }
#pragma unroll
      for (int c = 0; c < 8; ++c) {  // B: 128 cols x 64B
        int idx = c * 16 + rr;
        const char* src = (const char*)gB + (size_t)idx * 512 + kt * 64 + kg * 16;
        gload_lds16((void*)src, (char*)lB + c * 1024);
      }
    }
    __syncthreads();
    bf16x8 a_hi[4], a_lo[4], b_hi[4], b_lo[4];
#pragma unroll
    for (int m = 0; m < 4; ++m) {
      int row = m * 16 + fr;
      a_hi[m] = *reinterpret_cast<const bf16x8*>((const char*)sAhi + row * 64 + fkb);
      a_lo[m] = *reinterpret_cast<const bf16x8*>((const char*)sAlo + row * 64 + fkb);
    }
#pragma unroll
    for (int n = 0; n < 4; ++n) {
      int col = wc + n * 16 + fr;
      b_hi[n] = *reinterpret_cast<const bf16x8*>((const char*)sBhi + col * 64 + fkb);
      b_lo[n] = *reinterpret_cast<const bf16x8*>((const char*)sBlo + col * 64 + fkb);
    }
#pragma unroll
    for (int m = 0; m < 4; ++m)
#pragma unroll
      for (int n = 0; n < 4; ++n) {
        acc[m][n] = __builtin_amdgcn_mfma_f32_16x16x32_bf16(a_hi[m], b_hi[n], acc[m][n], 0, 0, 0);
        acc[m][n] = __builtin_amdgcn_mfma_f32_16x16x32_bf16(a_hi[m], b_lo[n], acc[m][n], 0, 0, 0);
        acc[m][n] = __builtin_amdgcn_mfma_f32_16x16x32_bf16(a_lo[m], b_hi[n], acc[m][n], 0, 0, 0);
      }
    __syncthreads();
  }

  float bv[4];
#pragma unroll
  for (int n = 0; n < 4; ++n) bv[n] = bias[wc + n * 16 + (lane & 15)];
#pragma unroll
  for (int m = 0; m < 4; ++m) {
#pragma unroll
    for (int n = 0; n < 4; ++n) {
#pragma unroll
      for (int j = 0; j < 4; ++j) {
        int row_l = m * 16 + (lane >> 4) * 4 + j;
        int g = block_row + row_l;
        if (g < N) {
          int col = wc + n * 16 + (lane & 15);
          float v = fmaxf(acc[m][n][j] + bv[n], 0.f);
          unsigned short h = f32_to_bf16(v);
          Ohi[(size_t)g * 128 + col] = h;
          Olo[(size_t)g * 128 + col] = f32_to_bf16(v - bf16_to_f32(h));
        }
      }
    }
  }
}

// Final: Out[N][16] = H[N][128] @ W[128][16] + b; H reconstructed from hi+lo.
__global__ __launch_bounds__(256) void k_final(const unsigned short* __restrict__ Hhi,
                                               const unsigned short* __restrict__ Hlo,
                                               const float* __restrict__ W,
                                               const float* __restrict__ b,
                                               float* __restrict__ Out, int N) {
  __shared__ float sH[16][128];
  __shared__ float sW[128][16];
  __shared__ float sb[16];
  int t = threadIdx.x;
  int node0 = blockIdx.x * 16;
  {
    int row = t >> 4, q = t & 15;  // 8 elems each
    int g = node0 + row;
    if (g < N) {
      uint4 hv = *reinterpret_cast<const uint4*>(&Hhi[(size_t)g * 128 + q * 8]);
      uint4 lv = *reinterpret_cast<const uint4*>(&Hlo[(size_t)g * 128 + q * 8]);
      const unsigned short* hp = (const unsigned short*)&hv;
      const unsigned short* lp = (const unsigned short*)&lv;
#pragma unroll
      for (int e = 0; e < 8; ++e)
        sH[row][q * 8 + e] = bf16_to_f32(hp[e]) + bf16_to_f32(lp[e]);
    } else {
#pragma unroll
      for (int e = 0; e < 8; ++e) sH[row][q * 8 + e] = 0.f;
    }
  }
  for (int j = t; j < 512; j += 256) {
    int row = j >> 2, q = j & 3;
    *reinterpret_cast<float4*>(&sW[row][q * 4]) =
        *reinterpret_cast<const float4*>(&W[(size_t)row * 16 + q * 4]);
  }
  if (t < 16) sb[t] = b[t];
  __syncthreads();
  int node = t >> 4, col = t & 15;
  float acc = sb[col];
#pragma unroll 8
  for (int k = 0; k < 128; ++k) acc = fmaf(sH[node][k], sW[k][col], acc);
  int g = node0 + node;
  if (g < N) Out[(size_t)g * 16 + col] = acc;
}

extern "C" void kernel_launch(void* const* d_in, const int* in_sizes, int n_in,
                              void* d_out, int out_size, void* d_ws, size_t ws_size,
                              hipStream_t stream) {
  if (n_in < 13) return;
  const float* x = (const float*)d_in[0];
  const int* ei = (const int*)d_in[1];
  const float* W1l = (const float*)d_in[2];
  const float* b1 = (const float*)d_in[3];
  const float* W1r = (const float*)d_in[4];
  const float* W2l = (const float*)d_in[5];
  const float* b2 = (const float*)d_in[6];
  const float* W2r = (const float*)d_in[7];
  const float* W3l = (const float*)d_in[8];
  const float* b3 = (const float*)d_in[9];
  const float* W3r = (const float*)d_in[10];
  const float* Wlin = (const float*)d_in[11];
  const float* blin = (const float*)d_in[12];
  float* out = (float*)d_out;

  const int N = in_sizes[0] / 128;
  const int E = in_sizes[1] / 2;

  char* w = (char*)d_ws;
  size_t off = 0;
  auto alloc = [&](size_t bytes) -> void* {
    off = (off + 255) & ~(size_t)255;
    void* p = (void*)(w + off);
    off += bytes;
    return p;
  };
  size_t actB = (size_t)N * 128 * 2;
  unsigned short* Xhi = (unsigned short*)alloc(actB);
  unsigned short* Xlo = (unsigned short*)alloc(actB);
  unsigned short* Ahi = (unsigned short*)alloc(actB);
  unsigned short* Alo = (unsigned short*)alloc(actB);
  unsigned short* Mhi = (unsigned short*)alloc(actB);
  unsigned short* Mlo = (unsigned short*)alloc(actB);
  unsigned short* Wt[6];
  for (int i = 0; i < 6; ++i) Wt[i] = (unsigned short*)alloc(128 * 256 * 2);
  int* deg = (int*)alloc((size_t)N * 4);
  int* row_ptr = (int*)alloc((size_t)(N + 1) * 4);
  int* col_idx = (int*)alloc((size_t)E * 4);
  int* erank = (int*)alloc((size_t)E * 4);
  float* invdeg = (float*)alloc((size_t)N * 4);
  int* flag = (int*)alloc(4);
  int* bsum = (int*)alloc((size_t)1024 * 4);
  (void)ws_size;

  const int nbScan = (N + 1023) / 1024;

  // CSR build + operand prep
  k_zero_i32<<<(N + 255) / 256, 256, 0, stream>>>(deg, N);
  k_zero_i32<<<1, 256, 0, stream>>>(flag, 1);
  k_detect<<<1, 256, 0, stream>>>(ei, flag);
  k_count<<<(E + 255) / 256, 256, 0, stream>>>(ei, flag, deg, erank, E);
  k_split<<<(N * 32 + 255) / 256, 256, 0, stream>>>(x, Xhi, Xlo, N * 32);
  k_prep_w<<<128, 256, 0, stream>>>(W1l, W1r, Wt[0], Wt[1]);
  k_prep_w<<<128, 256, 0, stream>>>(W2l, W2r, Wt[2], Wt[3]);
  k_prep_w<<<128, 256, 0, stream>>>(W3l, W3r, Wt[4], Wt[5]);
  k_scan1<<<nbScan, 256, 0, stream>>>(deg, bsum, N);
  k_scan2<<<1, 1024, 0, stream>>>(bsum, row_ptr, nbScan, N);
  k_scan3<<<nbScan, 256, 0, stream>>>(deg, bsum, row_ptr, invdeg, N);
  k_fill<<<(E + 255) / 256, 256, 0, stream>>>(ei, flag, row_ptr, erank, col_idx, E);

  int aggBlocks = (N * 64 + 255) / 256;
  int gemmBlocks = (N + 63) / 64;

  // layer 1: X -> A (h1)
  k_aggregate<<<aggBlocks, 256, 0, stream>>>(Xhi, row_ptr, col_idx, invdeg,
                                             (unsigned int*)Mhi, (unsigned int*)Mlo, N);
  k_mfma_gemm<<<gemmBlocks, 128, 0, stream>>>(Mhi, Mlo, Xhi, Xlo, Wt[0], Wt[1], b1,
                                              Ahi, Alo, N);
  // layer 2: A -> X (h2)
  k_aggregate<<<aggBlocks, 256, 0, stream>>>(Ahi, row_ptr, col_idx, invdeg,
                                             (unsigned int*)Mhi, (unsigned int*)Mlo, N);
  k_mfma_gemm<<<gemmBlocks, 128, 0, stream>>>(Mhi, Mlo, Ahi, Alo, Wt[2], Wt[3], b2,
                                              Xhi, Xlo, N);
  // layer 3: X -> A (h3)
  k_aggregate<<<aggBlocks, 256, 0, stream>>>(Xhi, row_ptr, col_idx, invdeg,
                                             (unsigned int*)Mhi, (unsigned int*)Mlo, N);
  k_mfma_gemm<<<gemmBlocks, 128, 0, stream>>>(Mhi, Mlo, Xhi, Xlo, Wt[4], Wt[5], b3,
                                              Ahi, Alo, N);
  // final linear
  k_final<<<(N + 15) / 16, 256, 0, stream>>>(Ahi, Alo, Wlin, blin, out, N);
}

// Round 9
// 282.449 us; speedup vs baseline: 1.0071x; 1.0071x over previous
//
#include <hip/hip_runtime.h>

// ---------------------------------------------------------------------------
// 3-layer GraphSAGE (mean aggregation) + final linear.
// N=50000, 128 ch hidden, 800000 edges, out 16.
// R4: split-bf16 (hi/lo) MFMA GEMMs, K=256 combined; CSR de-atomic'd fill.
// R5/R6 (REGRESSED, reverted): shfl-heavy agg / channel-sliced agg.
// R7: aggregate unroll-8 (276.6us). R8: agg unroll-16 + 64x128 GEMM (284.5us,
//     bundled regression — ambiguous attribution).
// R9: A/B decompose — agg back to R7 unroll-8; keep 64x128 2-wave GEMM.
//     R9-276.6 isolates the GEMM delta; 284.5-R9 isolates the unroll-16 delta.
// ---------------------------------------------------------------------------

typedef short bf16x8 __attribute__((ext_vector_type(8)));  // 8 bf16 (4 VGPRs)
typedef float f32x4 __attribute__((ext_vector_type(4)));

__device__ __forceinline__ float bf16_to_f32(unsigned int lo16) {
  unsigned int u = lo16 << 16;
  return __builtin_bit_cast(float, u);
}
__device__ __forceinline__ unsigned short f32_to_bf16(float f) {
  unsigned int u = __builtin_bit_cast(unsigned int, f);
  unsigned int r = (u + 0x7FFFu + ((u >> 16) & 1u)) >> 16;  // RNE
  return (unsigned short)r;
}

// async global->LDS, 16B per lane; lds base must be wave-uniform.
__device__ __forceinline__ void gload_lds16(void* g, void* lds_base) {
  __builtin_amdgcn_global_load_lds(
      (__attribute__((address_space(1))) unsigned int*)(uintptr_t)g,
      (__attribute__((address_space(3))) unsigned int*)(unsigned int)(uintptr_t)lds_base,
      16, 0, 0);
}

__global__ void k_zero_i32(int* __restrict__ p, int n) {
  int i = blockIdx.x * blockDim.x + threadIdx.x;
  if (i < n) p[i] = 0;
}

// fp32 -> bf16 hi/lo split, 4 elems/thread
__global__ __launch_bounds__(256) void k_split(const float* __restrict__ in,
                                               unsigned short* __restrict__ hi,
                                               unsigned short* __restrict__ lo, int n4) {
  int i = blockIdx.x * blockDim.x + threadIdx.x;
  if (i < n4) {
    float4 v = *reinterpret_cast<const float4*>(&in[(size_t)i * 4]);
    ushort4 h, l;
    h.x = f32_to_bf16(v.x); l.x = f32_to_bf16(v.x - bf16_to_f32(h.x));
    h.y = f32_to_bf16(v.y); l.y = f32_to_bf16(v.y - bf16_to_f32(h.y));
    h.z = f32_to_bf16(v.z); l.z = f32_to_bf16(v.z - bf16_to_f32(h.z));
    h.w = f32_to_bf16(v.w); l.w = f32_to_bf16(v.w - bf16_to_f32(h.w));
    *reinterpret_cast<ushort4*>(&hi[(size_t)i * 4]) = h;
    *reinterpret_cast<ushort4*>(&lo[(size_t)i * 4]) = l;
  }
}

// Weights: Wt[n][k] = (k<128 ? Wl[k][n] : Wr[k-128][n]), split hi/lo.
__global__ __launch_bounds__(256) void k_prep_w(const float* __restrict__ Wl,
                                                const float* __restrict__ Wr,
                                                unsigned short* __restrict__ Whi,
                                                unsigned short* __restrict__ Wlo) {
  int n = blockIdx.x, k = threadIdx.x;  // 128 blocks x 256 threads
  float v = (k < 128) ? Wl[(size_t)k * 128 + n] : Wr[(size_t)(k - 128) * 128 + n];
  unsigned short h = f32_to_bf16(v);
  Whi[(size_t)n * 256 + k] = h;
  Wlo[(size_t)n * 256 + k] = f32_to_bf16(v - bf16_to_f32(h));
}

// int32-vs-int64 edge_index detection
__global__ void k_detect(const int* __restrict__ ei, int* __restrict__ flag) {
  int t = threadIdx.x;
  int any = 0;
  for (int i = t; i < 1024; i += 256)
    if (ei[2 * i + 1] != 0) any = 1;
  if (any) atomicOr(flag, 1);
}

__device__ __forceinline__ int load_src(const int* ei, int E, int i, int is32) {
  return is32 ? ei[i] : ei[2 * i];
}
__device__ __forceinline__ int load_dst(const int* ei, int E, int i, int is32) {
  return is32 ? ei[E + i] : ei[2 * E + 2 * i];
}

// count degree + capture per-edge rank (removes atomic from k_fill)
__global__ __launch_bounds__(256) void k_count(const int* __restrict__ ei,
                                               const int* __restrict__ flag,
                                               int* __restrict__ deg,
                                               int* __restrict__ erank, int E) {
  int i = blockIdx.x * blockDim.x + threadIdx.x;
  if (i < E) {
    int is32 = *flag;
    erank[i] = atomicAdd(&deg[load_dst(ei, E, i, is32)], 1);
  }
}

// --- device-wide exclusive scan over deg (3 passes, 1024 elems/block) ------
__global__ __launch_bounds__(256) void k_scan1(const int* __restrict__ deg,
                                               int* __restrict__ bsum, int N) {
  __shared__ int s[256];
  int t = threadIdx.x;
  int base = blockIdx.x * 1024 + t * 4;
  int v = 0;
#pragma unroll
  for (int j = 0; j < 4; ++j) {
    int i = base + j;
    v += (i < N) ? deg[i] : 0;
  }
  s[t] = v;
  __syncthreads();
  for (int off = 128; off > 0; off >>= 1) {
    if (t < off) s[t] += s[t + off];
    __syncthreads();
  }
  if (t == 0) bsum[blockIdx.x] = s[0];
}

__global__ __launch_bounds__(1024) void k_scan2(int* __restrict__ bsum,
                                                int* __restrict__ row_ptr,
                                                int nb, int N) {
  __shared__ int s[1024];
  int t = threadIdx.x;
  int v = (t < nb) ? bsum[t] : 0;
  s[t] = v;
  __syncthreads();
  for (int off = 1; off < 1024; off <<= 1) {
    int add = (t >= off) ? s[t - off] : 0;
    __syncthreads();
    s[t] += add;
    __syncthreads();
  }
  if (t < nb) bsum[t] = s[t] - v;  // exclusive
  if (t == 1023) row_ptr[N] = s[1023];
}

__global__ __launch_bounds__(256) void k_scan3(const int* __restrict__ deg,
                                               const int* __restrict__ bsum,
                                               int* __restrict__ row_ptr,
                                               float* __restrict__ inv_deg, int N) {
  __shared__ int s[256];
  int t = threadIdx.x;
  int base = blockIdx.x * 1024 + t * 4;
  int v[4];
  int sum = 0;
#pragma unroll
  for (int j = 0; j < 4; ++j) {
    int i = base + j;
    v[j] = (i < N) ? deg[i] : 0;
    sum += v[j];
  }
  s[t] = sum;
  __syncthreads();
  for (int off = 1; off < 256; off <<= 1) {
    int add = (t >= off) ? s[t - off] : 0;
    __syncthreads();
    s[t] += add;
    __syncthreads();
  }
  int excl = s[t] - sum + bsum[blockIdx.x];
#pragma unroll
  for (int j = 0; j < 4; ++j) {
    int i = base + j;
    if (i < N) {
      row_ptr[i] = excl;
      inv_deg[i] = 1.0f / (float)((v[j] > 1) ? v[j] : 1);
      excl += v[j];
    }
  }
}

// pure scatter fill (rank precomputed)
__global__ __launch_bounds__(256) void k_fill(const int* __restrict__ ei,
                                              const int* __restrict__ flag,
                                              const int* __restrict__ row_ptr,
                                              const int* __restrict__ erank,
                                              int* __restrict__ col_idx, int E) {
  int i = blockIdx.x * blockDim.x + threadIdx.x;
  if (i < E) {
    int is32 = *flag;
    int d = load_dst(ei, E, i, is32);
    int s = load_src(ei, E, i, is32);
    col_idx[row_ptr[d] + erank[i]] = s;
  }
}

// One wave per node, 4B/lane = full 256B row per load, unroll-8 (8 gathers in
// flight), per-lane hi/lo packed stores. No shuffles, no LDS. (R7 body.)
__global__ __launch_bounds__(256) void k_aggregate(const unsigned short* __restrict__ Xhi,
                                                   const int* __restrict__ row_ptr,
                                                   const int* __restrict__ col_idx,
                                                   const float* __restrict__ inv_deg,
                                                   unsigned int* __restrict__ Mhi,
                                                   unsigned int* __restrict__ Mlo, int N) {
  int gw = (int)((blockIdx.x * blockDim.x + threadIdx.x) >> 6);
  int lane = threadIdx.x & 63;
  if (gw >= N) return;
  int s = row_ptr[gw], e = row_ptr[gw + 1];
  const unsigned int* Xp =
      reinterpret_cast<const unsigned int*>(Xhi) + lane;  // row stride 64 u32
  float ax[8], ay[8];
#pragma unroll
  for (int q = 0; q < 8; ++q) { ax[q] = 0.f; ay[q] = 0.f; }
  int j = s;
  for (; j + 8 <= e; j += 8) {
    unsigned int v[8];
#pragma unroll
    for (int q = 0; q < 8; ++q) v[q] = Xp[(size_t)col_idx[j + q] * 64];
#pragma unroll
    for (int q = 0; q < 8; ++q) {
      ax[q] += bf16_to_f32(v[q] & 0xFFFFu);
      ay[q] += bf16_to_f32(v[q] >> 16);
    }
  }
  for (; j + 4 <= e; j += 4) {
    unsigned int v[4];
#pragma unroll
    for (int q = 0; q < 4; ++q) v[q] = Xp[(size_t)col_idx[j + q] * 64];
#pragma unroll
    for (int q = 0; q < 4; ++q) {
      ax[q] += bf16_to_f32(v[q] & 0xFFFFu);
      ay[q] += bf16_to_f32(v[q] >> 16);
    }
  }
  for (; j < e; ++j) {
    unsigned int v = Xp[(size_t)col_idx[j] * 64];
    ax[0] += bf16_to_f32(v & 0xFFFFu);
    ay[0] += bf16_to_f32(v >> 16);
  }
  float inv = inv_deg[gw];
  float rx = ((ax[0] + ax[1]) + (ax[2] + ax[3])) + ((ax[4] + ax[5]) + (ax[6] + ax[7]));
  float ry = ((ay[0] + ay[1]) + (ay[2] + ay[3])) + ((ay[4] + ay[5]) + (ay[6] + ay[7]));
  rx *= inv;
  ry *= inv;
  unsigned int hx = f32_to_bf16(rx), hy = f32_to_bf16(ry);
  unsigned int lx = f32_to_bf16(rx - bf16_to_f32(hx));
  unsigned int ly = f32_to_bf16(ry - bf16_to_f32(hy));
  Mhi[(size_t)gw * 64 + lane] = hx | (hy << 16);
  Mlo[(size_t)gw * 64 + lane] = lx | (ly << 16);
}

// MFMA GEMM: Out = relu([A1 | A2](N x 256) @ Wt^T + bias), split-bf16 3-pass.
// Block: 64 rows x 128 cols, 2 waves (cols split), wave = 64x64 via 4x4
// 16x16x32 MFMA. 782 blocks = 3.05/CU (balanced). Wave0 stages hi, wave1 lo.
__global__ __launch_bounds__(128) void k_mfma_gemm(
    const unsigned short* __restrict__ A1hi, const unsigned short* __restrict__ A1lo,
    const unsigned short* __restrict__ A2hi, const unsigned short* __restrict__ A2lo,
    const unsigned short* __restrict__ Whi, const unsigned short* __restrict__ Wlo,
    const float* __restrict__ bias,
    unsigned short* __restrict__ Ohi, unsigned short* __restrict__ Olo, int N) {
  __shared__ unsigned short sAhi[64 * 32], sAlo[64 * 32];    // 4KB each
  __shared__ unsigned short sBhi[128 * 32], sBlo[128 * 32];  // 8KB each
  int t = threadIdx.x;
  int lane = t & 63;
  int w = t >> 6;   // 0: hi stager, 1: lo stager
  int wc = w * 64;  // output col offset of this wave
  int block_row = blockIdx.x * 64;

  f32x4 acc[4][4];
#pragma unroll
  for (int m = 0; m < 4; ++m)
#pragma unroll
    for (int n = 0; n < 4; ++n) acc[m][n] = f32x4{0.f, 0.f, 0.f, 0.f};

  int kg = lane & 3;           // 16B group within 64B row
  int rr = lane >> 2;          // 0..15 row-within-chunk
  int fr = lane & 15;          // fragment row/col
  int fkb = (lane >> 4) * 16;  // fragment k byte offset

  for (int kt = 0; kt < 8; ++kt) {
    {
      const unsigned short* gA = (w == 0) ? ((kt < 4) ? A1hi : A2hi)
                                          : ((kt < 4) ? A1lo : A2lo);
      const unsigned short* gB = (w == 0) ? Whi : Wlo;
      unsigned short* lA = (w == 0) ? sAhi : sAlo;
      unsigned short* lB = (w == 0) ? sBhi : sBlo;
#pragma unroll
      for (int c = 0; c < 4; ++c) {  // A: 64 rows x 64B
        int idx = c * 16 + rr;
        int rg = block_row + idx;
        if (rg > N - 1) rg = N - 1;
        const char* src = (const char*)gA + (size_t)rg * 256 + (kt & 3) * 64 + kg * 16;
        gload_lds16((void*)src, (char*)lA + c * 1024);
      }
#pragma unroll
      for (int c = 0; c < 8; ++c) {  // B: 128 cols x 64B
        int idx = c * 16 + rr;
        const char* src = (const char*)gB + (size_t)idx * 512 + kt * 64 + kg * 16;
        gload_lds16((void*)src, (char*)lB + c * 1024);
      }
    }
    __syncthreads();
    bf16x8 a_hi[4], a_lo[4], b_hi[4], b_lo[4];
#pragma unroll
    for (int m = 0; m < 4; ++m) {
      int row = m * 16 + fr;
      a_hi[m] = *reinterpret_cast<const bf16x8*>((const char*)sAhi + row * 64 + fkb);
      a_lo[m] = *reinterpret_cast<const bf16x8*>((const char*)sAlo + row * 64 + fkb);
    }
#pragma unroll
    for (int n = 0; n < 4; ++n) {
      int col = wc + n * 16 + fr;
      b_hi[n] = *reinterpret_cast<const bf16x8*>((const char*)sBhi + col * 64 + fkb);
      b_lo[n] = *reinterpret_cast<const bf16x8*>((const char*)sBlo + col * 64 + fkb);
    }
#pragma unroll
    for (int m = 0; m < 4; ++m)
#pragma unroll
      for (int n = 0; n < 4; ++n) {
        acc[m][n] = __builtin_amdgcn_mfma_f32_16x16x32_bf16(a_hi[m], b_hi[n], acc[m][n], 0, 0, 0);
        acc[m][n] = __builtin_amdgcn_mfma_f32_16x16x32_bf16(a_hi[m], b_lo[n], acc[m][n], 0, 0, 0);
        acc[m][n] = __builtin_amdgcn_mfma_f32_16x16x32_bf16(a_lo[m], b_hi[n], acc[m][n], 0, 0, 0);
      }
    __syncthreads();
  }

  float bv[4];
#pragma unroll
  for (int n = 0; n < 4; ++n) bv[n] = bias[wc + n * 16 + (lane & 15)];
#pragma unroll
  for (int m = 0; m < 4; ++m) {
#pragma unroll
    for (int n = 0; n < 4; ++n) {
#pragma unroll
      for (int j = 0; j < 4; ++j) {
        int row_l = m * 16 + (lane >> 4) * 4 + j;
        int g = block_row + row_l;
        if (g < N) {
          int col = wc + n * 16 + (lane & 15);
          float v = fmaxf(acc[m][n][j] + bv[n], 0.f);
          unsigned short h = f32_to_bf16(v);
          Ohi[(size_t)g * 128 + col] = h;
          Olo[(size_t)g * 128 + col] = f32_to_bf16(v - bf16_to_f32(h));
        }
      }
    }
  }
}

// Final: Out[N][16] = H[N][128] @ W[128][16] + b; H reconstructed from hi+lo.
__global__ __launch_bounds__(256) void k_final(const unsigned short* __restrict__ Hhi,
                                               const unsigned short* __restrict__ Hlo,
                                               const float* __restrict__ W,
                                               const float* __restrict__ b,
                                               float* __restrict__ Out, int N) {
  __shared__ float sH[16][128];
  __shared__ float sW[128][16];
  __shared__ float sb[16];
  int t = threadIdx.x;
  int node0 = blockIdx.x * 16;
  {
    int row = t >> 4, q = t & 15;  // 8 elems each
    int g = node0 + row;
    if (g < N) {
      uint4 hv = *reinterpret_cast<const uint4*>(&Hhi[(size_t)g * 128 + q * 8]);
      uint4 lv = *reinterpret_cast<const uint4*>(&Hlo[(size_t)g * 128 + q * 8]);
      const unsigned short* hp = (const unsigned short*)&hv;
      const unsigned short* lp = (const unsigned short*)&lv;
#pragma unroll
      for (int e = 0; e < 8; ++e)
        sH[row][q * 8 + e] = bf16_to_f32(hp[e]) + bf16_to_f32(lp[e]);
    } else {
#pragma unroll
      for (int e = 0; e < 8; ++e) sH[row][q * 8 + e] = 0.f;
    }
  }
  for (int j = t; j < 512; j += 256) {
    int row = j >> 2, q = j & 3;
    *reinterpret_cast<float4*>(&sW[row][q * 4]) =
        *reinterpret_cast<const float4*>(&W[(size_t)row * 16 + q * 4]);
  }
  if (t < 16) sb[t] = b[t];
  __syncthreads();
  int node = t >> 4, col = t & 15;
  float acc = sb[col];
#pragma unroll 8
  for (int k = 0; k < 128; ++k) acc = fmaf(sH[node][k], sW[k][col], acc);
  int g = node0 + node;
  if (g < N) Out[(size_t)g * 16 + col] = acc;
}

extern "C" void kernel_launch(void* const* d_in, const int* in_sizes, int n_in,
                              void* d_out, int out_size, void* d_ws, size_t ws_size,
                              hipStream_t stream) {
  if (n_in < 13) return;
  const float* x = (const float*)d_in[0];
  const int* ei = (const int*)d_in[1];
  const float* W1l = (const float*)d_in[2];
  const float* b1 = (const float*)d_in[3];
  const float* W1r = (const float*)d_in[4];
  const float* W2l = (const float*)d_in[5];
  const float* b2 = (const float*)d_in[6];
  const float* W2r = (const float*)d_in[7];
  const float* W3l = (const float*)d_in[8];
  const float* b3 = (const float*)d_in[9];
  const float* W3r = (const float*)d_in[10];
  const float* Wlin = (const float*)d_in[11];
  const float* blin = (const float*)d_in[12];
  float* out = (float*)d_out;

  const int N = in_sizes[0] / 128;
  const int E = in_sizes[1] / 2;

  char* w = (char*)d_ws;
  size_t off = 0;
  auto alloc = [&](size_t bytes) -> void* {
    off = (off + 255) & ~(size_t)255;
    void* p = (void*)(w + off);
    off += bytes;
    return p;
  };
  size_t actB = (size_t)N * 128 * 2;
  unsigned short* Xhi = (unsigned short*)alloc(actB);
  unsigned short* Xlo = (unsigned short*)alloc(actB);
  unsigned short* Ahi = (unsigned short*)alloc(actB);
  unsigned short* Alo = (unsigned short*)alloc(actB);
  unsigned short* Mhi = (unsigned short*)alloc(actB);
  unsigned short* Mlo = (unsigned short*)alloc(actB);
  unsigned short* Wt[6];
  for (int i = 0; i < 6; ++i) Wt[i] = (unsigned short*)alloc(128 * 256 * 2);
  int* deg = (int*)alloc((size_t)N * 4);
  int* row_ptr = (int*)alloc((size_t)(N + 1) * 4);
  int* col_idx = (int*)alloc((size_t)E * 4);
  int* erank = (int*)alloc((size_t)E * 4);
  float* invdeg = (float*)alloc((size_t)N * 4);
  int* flag = (int*)alloc(4);
  int* bsum = (int*)alloc((size_t)1024 * 4);
  (void)ws_size;

  const int nbScan = (N + 1023) / 1024;

  // CSR build + operand prep
  k_zero_i32<<<(N + 255) / 256, 256, 0, stream>>>(deg, N);
  k_zero_i32<<<1, 256, 0, stream>>>(flag, 1);
  k_detect<<<1, 256, 0, stream>>>(ei, flag);
  k_count<<<(E + 255) / 256, 256, 0, stream>>>(ei, flag, deg, erank, E);
  k_split<<<(N * 32 + 255) / 256, 256, 0, stream>>>(x, Xhi, Xlo, N * 32);
  k_prep_w<<<128, 256, 0, stream>>>(W1l, W1r, Wt[0], Wt[1]);
  k_prep_w<<<128, 256, 0, stream>>>(W2l, W2r, Wt[2], Wt[3]);
  k_prep_w<<<128, 256, 0, stream>>>(W3l, W3r, Wt[4], Wt[5]);
  k_scan1<<<nbScan, 256, 0, stream>>>(deg, bsum, N);
  k_scan2<<<1, 1024, 0, stream>>>(bsum, row_ptr, nbScan, N);
  k_scan3<<<nbScan, 256, 0, stream>>>(deg, bsum, row_ptr, invdeg, N);
  k_fill<<<(E + 255) / 256, 256, 0, stream>>>(ei, flag, row_ptr, erank, col_idx, E);

  int aggBlocks = (N * 64 + 255) / 256;
  int gemmBlocks = (N + 63) / 64;

  // layer 1: X -> A (h1)
  k_aggregate<<<aggBlocks, 256, 0, stream>>>(Xhi, row_ptr, col_idx, invdeg,
                                             (unsigned int*)Mhi, (unsigned int*)Mlo, N);
  k_mfma_gemm<<<gemmBlocks, 128, 0, stream>>>(Mhi, Mlo, Xhi, Xlo, Wt[0], Wt[1], b1,
                                              Ahi, Alo, N);
  // layer 2: A -> X (h2)
  k_aggregate<<<aggBlocks, 256, 0, stream>>>(Ahi, row_ptr, col_idx, invdeg,
                                             (unsigned int*)Mhi, (unsigned int*)Mlo, N);
  k_mfma_gemm<<<gemmBlocks, 128, 0, stream>>>(Mhi, Mlo, Ahi, Alo, Wt[2], Wt[3], b2,
                                              Xhi, Xlo, N);
  // layer 3: X -> A (h3)
  k_aggregate<<<aggBlocks, 256, 0, stream>>>(Xhi, row_ptr, col_idx, invdeg,
                                             (unsigned int*)Mhi, (unsigned int*)Mlo, N);
  k_mfma_gemm<<<gemmBlocks, 128, 0, stream>>>(Mhi, Mlo, Xhi, Xlo, Wt[4], Wt[5], b3,
                                              Ahi, Alo, N);
  // final linear
  k_final<<<(N + 15) / 16, 256, 0, stream>>>(Ahi, Alo, Wlin, blin, out, N);
}

// Round 10
// 269.849 us; speedup vs baseline: 1.0541x; 1.0467x over previous
//
#include <hip/hip_runtime.h>

// ---------------------------------------------------------------------------
// 3-layer GraphSAGE (mean aggregation) + final linear.
// N=50000, 128 ch hidden, 800000 edges, out 16.
// R4: split-bf16 (hi/lo) MFMA GEMMs, K=256 combined; CSR de-atomic'd fill.
// R5/R6/R8 (REGRESSED, reverted): shfl agg / sliced agg / unroll-16+64x128.
// R7 = best known (276.6us): agg unroll-8, 128x128 4-wave GEMM.
// R9 A/B: 64x128 GEMM = +5.8us, unroll-16 = +2.1us. Both reverted.
// R10: R7 + ONE change: GEMM kt-loop double-buffered (2-phase T3-minimum).
//      Stage kt+1 into buf^1 before computing kt; 1 barrier/iter.
//      LDS 32->64KB (2 blocks/CU) — overlap vs occupancy bet.
// ---------------------------------------------------------------------------

typedef short bf16x8 __attribute__((ext_vector_type(8)));  // 8 bf16 (4 VGPRs)
typedef float f32x4 __attribute__((ext_vector_type(4)));

__device__ __forceinline__ float bf16_to_f32(unsigned int lo16) {
  unsigned int u = lo16 << 16;
  return __builtin_bit_cast(float, u);
}
__device__ __forceinline__ unsigned short f32_to_bf16(float f) {
  unsigned int u = __builtin_bit_cast(unsigned int, f);
  unsigned int r = (u + 0x7FFFu + ((u >> 16) & 1u)) >> 16;  // RNE
  return (unsigned short)r;
}

// async global->LDS, 16B per lane; lds base must be wave-uniform.
__device__ __forceinline__ void gload_lds16(const void* g, void* lds_base) {
  __builtin_amdgcn_global_load_lds(
      (__attribute__((address_space(1))) unsigned int*)(uintptr_t)g,
      (__attribute__((address_space(3))) unsigned int*)(unsigned int)(uintptr_t)lds_base,
      16, 0, 0);
}

__global__ void k_zero_i32(int* __restrict__ p, int n) {
  int i = blockIdx.x * blockDim.x + threadIdx.x;
  if (i < n) p[i] = 0;
}

// fp32 -> bf16 hi/lo split, 4 elems/thread
__global__ __launch_bounds__(256) void k_split(const float* __restrict__ in,
                                               unsigned short* __restrict__ hi,
                                               unsigned short* __restrict__ lo, int n4) {
  int i = blockIdx.x * blockDim.x + threadIdx.x;
  if (i < n4) {
    float4 v = *reinterpret_cast<const float4*>(&in[(size_t)i * 4]);
    ushort4 h, l;
    h.x = f32_to_bf16(v.x); l.x = f32_to_bf16(v.x - bf16_to_f32(h.x));
    h.y = f32_to_bf16(v.y); l.y = f32_to_bf16(v.y - bf16_to_f32(h.y));
    h.z = f32_to_bf16(v.z); l.z = f32_to_bf16(v.z - bf16_to_f32(h.z));
    h.w = f32_to_bf16(v.w); l.w = f32_to_bf16(v.w - bf16_to_f32(h.w));
    *reinterpret_cast<ushort4*>(&hi[(size_t)i * 4]) = h;
    *reinterpret_cast<ushort4*>(&lo[(size_t)i * 4]) = l;
  }
}

// Weights: Wt[n][k] = (k<128 ? Wl[k][n] : Wr[k-128][n]), split hi/lo.
__global__ __launch_bounds__(256) void k_prep_w(const float* __restrict__ Wl,
                                                const float* __restrict__ Wr,
                                                unsigned short* __restrict__ Whi,
                                                unsigned short* __restrict__ Wlo) {
  int n = blockIdx.x, k = threadIdx.x;  // 128 blocks x 256 threads
  float v = (k < 128) ? Wl[(size_t)k * 128 + n] : Wr[(size_t)(k - 128) * 128 + n];
  unsigned short h = f32_to_bf16(v);
  Whi[(size_t)n * 256 + k] = h;
  Wlo[(size_t)n * 256 + k] = f32_to_bf16(v - bf16_to_f32(h));
}

// int32-vs-int64 edge_index detection
__global__ void k_detect(const int* __restrict__ ei, int* __restrict__ flag) {
  int t = threadIdx.x;
  int any = 0;
  for (int i = t; i < 1024; i += 256)
    if (ei[2 * i + 1] != 0) any = 1;
  if (any) atomicOr(flag, 1);
}

__device__ __forceinline__ int load_src(const int* ei, int E, int i, int is32) {
  return is32 ? ei[i] : ei[2 * i];
}
__device__ __forceinline__ int load_dst(const int* ei, int E, int i, int is32) {
  return is32 ? ei[E + i] : ei[2 * E + 2 * i];
}

// count degree + capture per-edge rank (removes atomic from k_fill)
__global__ __launch_bounds__(256) void k_count(const int* __restrict__ ei,
                                               const int* __restrict__ flag,
                                               int* __restrict__ deg,
                                               int* __restrict__ erank, int E) {
  int i = blockIdx.x * blockDim.x + threadIdx.x;
  if (i < E) {
    int is32 = *flag;
    erank[i] = atomicAdd(&deg[load_dst(ei, E, i, is32)], 1);
  }
}

// --- device-wide exclusive scan over deg (3 passes, 1024 elems/block) ------
__global__ __launch_bounds__(256) void k_scan1(const int* __restrict__ deg,
                                               int* __restrict__ bsum, int N) {
  __shared__ int s[256];
  int t = threadIdx.x;
  int base = blockIdx.x * 1024 + t * 4;
  int v = 0;
#pragma unroll
  for (int j = 0; j < 4; ++j) {
    int i = base + j;
    v += (i < N) ? deg[i] : 0;
  }
  s[t] = v;
  __syncthreads();
  for (int off = 128; off > 0; off >>= 1) {
    if (t < off) s[t] += s[t + off];
    __syncthreads();
  }
  if (t == 0) bsum[blockIdx.x] = s[0];
}

__global__ __launch_bounds__(1024) void k_scan2(int* __restrict__ bsum,
                                                int* __restrict__ row_ptr,
                                                int nb, int N) {
  __shared__ int s[1024];
  int t = threadIdx.x;
  int v = (t < nb) ? bsum[t] : 0;
  s[t] = v;
  __syncthreads();
  for (int off = 1; off < 1024; off <<= 1) {
    int add = (t >= off) ? s[t - off] : 0;
    __syncthreads();
    s[t] += add;
    __syncthreads();
  }
  if (t < nb) bsum[t] = s[t] - v;  // exclusive
  if (t == 1023) row_ptr[N] = s[1023];
}

__global__ __launch_bounds__(256) void k_scan3(const int* __restrict__ deg,
                                               const int* __restrict__ bsum,
                                               int* __restrict__ row_ptr,
                                               float* __restrict__ inv_deg, int N) {
  __shared__ int s[256];
  int t = threadIdx.x;
  int base = blockIdx.x * 1024 + t * 4;
  int v[4];
  int sum = 0;
#pragma unroll
  for (int j = 0; j < 4; ++j) {
    int i = base + j;
    v[j] = (i < N) ? deg[i] : 0;
    sum += v[j];
  }
  s[t] = sum;
  __syncthreads();
  for (int off = 1; off < 256; off <<= 1) {
    int add = (t >= off) ? s[t - off] : 0;
    __syncthreads();
    s[t] += add;
    __syncthreads();
  }
  int excl = s[t] - sum + bsum[blockIdx.x];
#pragma unroll
  for (int j = 0; j < 4; ++j) {
    int i = base + j;
    if (i < N) {
      row_ptr[i] = excl;
      inv_deg[i] = 1.0f / (float)((v[j] > 1) ? v[j] : 1);
      excl += v[j];
    }
  }
}

// pure scatter fill (rank precomputed)
__global__ __launch_bounds__(256) void k_fill(const int* __restrict__ ei,
                                              const int* __restrict__ flag,
                                              const int* __restrict__ row_ptr,
                                              const int* __restrict__ erank,
                                              int* __restrict__ col_idx, int E) {
  int i = blockIdx.x * blockDim.x + threadIdx.x;
  if (i < E) {
    int is32 = *flag;
    int d = load_dst(ei, E, i, is32);
    int s = load_src(ei, E, i, is32);
    col_idx[row_ptr[d] + erank[i]] = s;
  }
}

// One wave per node, 4B/lane = full 256B row per load, unroll-8 (8 gathers in
// flight), per-lane hi/lo packed stores. No shuffles, no LDS. (R7 body.)
__global__ __launch_bounds__(256) void k_aggregate(const unsigned short* __restrict__ Xhi,
                                                   const int* __restrict__ row_ptr,
                                                   const int* __restrict__ col_idx,
                                                   const float* __restrict__ inv_deg,
                                                   unsigned int* __restrict__ Mhi,
                                                   unsigned int* __restrict__ Mlo, int N) {
  int gw = (int)((blockIdx.x * blockDim.x + threadIdx.x) >> 6);
  int lane = threadIdx.x & 63;
  if (gw >= N) return;
  int s = row_ptr[gw], e = row_ptr[gw + 1];
  const unsigned int* Xp =
      reinterpret_cast<const unsigned int*>(Xhi) + lane;  // row stride 64 u32
  float ax[8], ay[8];
#pragma unroll
  for (int q = 0; q < 8; ++q) { ax[q] = 0.f; ay[q] = 0.f; }
  int j = s;
  for (; j + 8 <= e; j += 8) {
    unsigned int v[8];
#pragma unroll
    for (int q = 0; q < 8; ++q) v[q] = Xp[(size_t)col_idx[j + q] * 64];
#pragma unroll
    for (int q = 0; q < 8; ++q) {
      ax[q] += bf16_to_f32(v[q] & 0xFFFFu);
      ay[q] += bf16_to_f32(v[q] >> 16);
    }
  }
  for (; j + 4 <= e; j += 4) {
    unsigned int v[4];
#pragma unroll
    for (int q = 0; q < 4; ++q) v[q] = Xp[(size_t)col_idx[j + q] * 64];
#pragma unroll
    for (int q = 0; q < 4; ++q) {
      ax[q] += bf16_to_f32(v[q] & 0xFFFFu);
      ay[q] += bf16_to_f32(v[q] >> 16);
    }
  }
  for (; j < e; ++j) {
    unsigned int v = Xp[(size_t)col_idx[j] * 64];
    ax[0] += bf16_to_f32(v & 0xFFFFu);
    ay[0] += bf16_to_f32(v >> 16);
  }
  float inv = inv_deg[gw];
  float rx = ((ax[0] + ax[1]) + (ax[2] + ax[3])) + ((ax[4] + ax[5]) + (ax[6] + ax[7]));
  float ry = ((ay[0] + ay[1]) + (ay[2] + ay[3])) + ((ay[4] + ay[5]) + (ay[6] + ay[7]));
  rx *= inv;
  ry *= inv;
  unsigned int hx = f32_to_bf16(rx), hy = f32_to_bf16(ry);
  unsigned int lx = f32_to_bf16(rx - bf16_to_f32(hx));
  unsigned int ly = f32_to_bf16(ry - bf16_to_f32(hy));
  Mhi[(size_t)gw * 64 + lane] = hx | (hy << 16);
  Mlo[(size_t)gw * 64 + lane] = lx | (ly << 16);
}

// MFMA GEMM: Out = relu([A1 | A2](N x 256) @ Wt^T + bias), split-bf16 3-pass.
// Block: 128 rows x 128 cols, 4 waves (2x2), wave = 64x64 via 4x4 16x16x32.
// R10: kt-loop double-buffered — stage kt+1 into buf^1 before computing kt;
// single __syncthreads per iter (its per-wave vmcnt drain lands after the
// loads flew under the ds_read+MFMA phase; also fences buffer reuse).
__global__ __launch_bounds__(256) void k_mfma_gemm(
    const unsigned short* __restrict__ A1hi, const unsigned short* __restrict__ A1lo,
    const unsigned short* __restrict__ A2hi, const unsigned short* __restrict__ A2lo,
    const unsigned short* __restrict__ Whi, const unsigned short* __restrict__ Wlo,
    const float* __restrict__ bias,
    unsigned short* __restrict__ Ohi, unsigned short* __restrict__ Olo, int N) {
  __shared__ unsigned short sAhi[2][128 * 32], sAlo[2][128 * 32];  // 8KB each buf
  __shared__ unsigned short sBhi[2][128 * 32], sBlo[2][128 * 32];
  int t = threadIdx.x;
  int lane = t & 63;
  int w = t >> 6;
  int wr = (w >> 1) * 64, wc = (w & 1) * 64;
  int block_row = blockIdx.x * 128;

  f32x4 acc[4][4];
#pragma unroll
  for (int m = 0; m < 4; ++m)
#pragma unroll
    for (int n = 0; n < 4; ++n) acc[m][n] = f32x4{0.f, 0.f, 0.f, 0.f};

  int kg = lane & 3;           // 16B group within 64B row
  int rr = lane >> 2;          // 0..15 row-within-chunk
  int fr = lane & 15;          // fragment row/col
  int fkb = (lane >> 4) * 16;  // fragment k byte offset

  // per-wave staging: wave w fills one component (8 x 1KB chunks) of buf b.
  auto stage = [&](int kt, int b) {
    const unsigned short* gsrc;
    unsigned short* lbase;
    int isA = (w < 2);
    if (w == 0) { gsrc = (kt < 4) ? A1hi : A2hi; lbase = sAhi[b]; }
    else if (w == 1) { gsrc = (kt < 4) ? A1lo : A2lo; lbase = sAlo[b]; }
    else if (w == 2) { gsrc = Whi; lbase = sBhi[b]; }
    else { gsrc = Wlo; lbase = sBlo[b]; }
#pragma unroll
    for (int c = 0; c < 8; ++c) {
      int idx = c * 16 + rr;  // A: row; B: col
      const char* src;
      if (isA) {
        int rg = block_row + idx;
        if (rg > N - 1) rg = N - 1;
        src = (const char*)gsrc + (size_t)rg * 256 + (kt & 3) * 64 + kg * 16;
      } else {
        src = (const char*)gsrc + (size_t)idx * 512 + kt * 64 + kg * 16;
      }
      gload_lds16(src, (char*)lbase + c * 1024);
    }
  };

  stage(0, 0);
  __syncthreads();  // drains each wave's own loads; buf0 complete for all

  for (int kt = 0; kt < 8; ++kt) {
    int cur = kt & 1;
    if (kt < 7) stage(kt + 1, cur ^ 1);  // overlap with compute below
    bf16x8 a_hi[4], a_lo[4], b_hi[4], b_lo[4];
#pragma unroll
    for (int m = 0; m < 4; ++m) {
      int row = wr + m * 16 + fr;
      a_hi[m] = *reinterpret_cast<const bf16x8*>((const char*)sAhi[cur] + row * 64 + fkb);
      a_lo[m] = *reinterpret_cast<const bf16x8*>((const char*)sAlo[cur] + row * 64 + fkb);
    }
#pragma unroll
    for (int n = 0; n < 4; ++n) {
      int col = wc + n * 16 + fr;
      b_hi[n] = *reinterpret_cast<const bf16x8*>((const char*)sBhi[cur] + col * 64 + fkb);
      b_lo[n] = *reinterpret_cast<const bf16x8*>((const char*)sBlo[cur] + col * 64 + fkb);
    }
#pragma unroll
    for (int m = 0; m < 4; ++m)
#pragma unroll
      for (int n = 0; n < 4; ++n) {
        acc[m][n] = __builtin_amdgcn_mfma_f32_16x16x32_bf16(a_hi[m], b_hi[n], acc[m][n], 0, 0, 0);
        acc[m][n] = __builtin_amdgcn_mfma_f32_16x16x32_bf16(a_hi[m], b_lo[n], acc[m][n], 0, 0, 0);
        acc[m][n] = __builtin_amdgcn_mfma_f32_16x16x32_bf16(a_lo[m], b_hi[n], acc[m][n], 0, 0, 0);
      }
    __syncthreads();  // next buf staged+landed; cur free for overwrite
  }

  float bv[4];
#pragma unroll
  for (int n = 0; n < 4; ++n) bv[n] = bias[wc + n * 16 + (lane & 15)];
#pragma unroll
  for (int m = 0; m < 4; ++m) {
#pragma unroll
    for (int n = 0; n < 4; ++n) {
#pragma unroll
      for (int j = 0; j < 4; ++j) {
        int row_l = wr + m * 16 + (lane >> 4) * 4 + j;
        int g = block_row + row_l;
        if (g < N) {
          int col = wc + n * 16 + (lane & 15);
          float v = fmaxf(acc[m][n][j] + bv[n], 0.f);
          unsigned short h = f32_to_bf16(v);
          Ohi[(size_t)g * 128 + col] = h;
          Olo[(size_t)g * 128 + col] = f32_to_bf16(v - bf16_to_f32(h));
        }
      }
    }
  }
}

// Final: Out[N][16] = H[N][128] @ W[128][16] + b; H reconstructed from hi+lo.
__global__ __launch_bounds__(256) void k_final(const unsigned short* __restrict__ Hhi,
                                               const unsigned short* __restrict__ Hlo,
                                               const float* __restrict__ W,
                                               const float* __restrict__ b,
                                               float* __restrict__ Out, int N) {
  __shared__ float sH[16][128];
  __shared__ float sW[128][16];
  __shared__ float sb[16];
  int t = threadIdx.x;
  int node0 = blockIdx.x * 16;
  {
    int row = t >> 4, q = t & 15;  // 8 elems each
    int g = node0 + row;
    if (g < N) {
      uint4 hv = *reinterpret_cast<const uint4*>(&Hhi[(size_t)g * 128 + q * 8]);
      uint4 lv = *reinterpret_cast<const uint4*>(&Hlo[(size_t)g * 128 + q * 8]);
      const unsigned short* hp = (const unsigned short*)&hv;
      const unsigned short* lp = (const unsigned short*)&lv;
#pragma unroll
      for (int e = 0; e < 8; ++e)
        sH[row][q * 8 + e] = bf16_to_f32(hp[e]) + bf16_to_f32(lp[e]);
    } else {
#pragma unroll
      for (int e = 0; e < 8; ++e) sH[row][q * 8 + e] = 0.f;
    }
  }
  for (int j = t; j < 512; j += 256) {
    int row = j >> 2, q = j & 3;
    *reinterpret_cast<float4*>(&sW[row][q * 4]) =
        *reinterpret_cast<const float4*>(&W[(size_t)row * 16 + q * 4]);
  }
  if (t < 16) sb[t] = b[t];
  __syncthreads();
  int node = t >> 4, col = t & 15;
  float acc = sb[col];
#pragma unroll 8
  for (int k = 0; k < 128; ++k) acc = fmaf(sH[node][k], sW[k][col], acc);
  int g = node0 + node;
  if (g < N) Out[(size_t)g * 16 + col] = acc;
}

extern "C" void kernel_launch(void* const* d_in, const int* in_sizes, int n_in,
                              void* d_out, int out_size, void* d_ws, size_t ws_size,
                              hipStream_t stream) {
  if (n_in < 13) return;
  const float* x = (const float*)d_in[0];
  const int* ei = (const int*)d_in[1];
  const float* W1l = (const float*)d_in[2];
  const float* b1 = (const float*)d_in[3];
  const float* W1r = (const float*)d_in[4];
  const float* W2l = (const float*)d_in[5];
  const float* b2 = (const float*)d_in[6];
  const float* W2r = (const float*)d_in[7];
  const float* W3l = (const float*)d_in[8];
  const float* b3 = (const float*)d_in[9];
  const float* W3r = (const float*)d_in[10];
  const float* Wlin = (const float*)d_in[11];
  const float* blin = (const float*)d_in[12];
  float* out = (float*)d_out;

  const int N = in_sizes[0] / 128;
  const int E = in_sizes[1] / 2;

  char* w = (char*)d_ws;
  size_t off = 0;
  auto alloc = [&](size_t bytes) -> void* {
    off = (off + 255) & ~(size_t)255;
    void* p = (void*)(w + off);
    off += bytes;
    return p;
  };
  size_t actB = (size_t)N * 128 * 2;
  unsigned short* Xhi = (unsigned short*)alloc(actB);
  unsigned short* Xlo = (unsigned short*)alloc(actB);
  unsigned short* Ahi = (unsigned short*)alloc(actB);
  unsigned short* Alo = (unsigned short*)alloc(actB);
  unsigned short* Mhi = (unsigned short*)alloc(actB);
  unsigned short* Mlo = (unsigned short*)alloc(actB);
  unsigned short* Wt[6];
  for (int i = 0; i < 6; ++i) Wt[i] = (unsigned short*)alloc(128 * 256 * 2);
  int* deg = (int*)alloc((size_t)N * 4);
  int* row_ptr = (int*)alloc((size_t)(N + 1) * 4);
  int* col_idx = (int*)alloc((size_t)E * 4);
  int* erank = (int*)alloc((size_t)E * 4);
  float* invdeg = (float*)alloc((size_t)N * 4);
  int* flag = (int*)alloc(4);
  int* bsum = (int*)alloc((size_t)1024 * 4);
  (void)ws_size;

  const int nbScan = (N + 1023) / 1024;

  // CSR build + operand prep
  k_zero_i32<<<(N + 255) / 256, 256, 0, stream>>>(deg, N);
  k_zero_i32<<<1, 256, 0, stream>>>(flag, 1);
  k_detect<<<1, 256, 0, stream>>>(ei, flag);
  k_count<<<(E + 255) / 256, 256, 0, stream>>>(ei, flag, deg, erank, E);
  k_split<<<(N * 32 + 255) / 256, 256, 0, stream>>>(x, Xhi, Xlo, N * 32);
  k_prep_w<<<128, 256, 0, stream>>>(W1l, W1r, Wt[0], Wt[1]);
  k_prep_w<<<128, 256, 0, stream>>>(W2l, W2r, Wt[2], Wt[3]);
  k_prep_w<<<128, 256, 0, stream>>>(W3l, W3r, Wt[4], Wt[5]);
  k_scan1<<<nbScan, 256, 0, stream>>>(deg, bsum, N);
  k_scan2<<<1, 1024, 0, stream>>>(bsum, row_ptr, nbScan, N);
  k_scan3<<<nbScan, 256, 0, stream>>>(deg, bsum, row_ptr, invdeg, N);
  k_fill<<<(E + 255) / 256, 256, 0, stream>>>(ei, flag, row_ptr, erank, col_idx, E);

  int aggBlocks = (N * 64 + 255) / 256;
  int gemmBlocks = (N + 127) / 128;

  // layer 1: X -> A (h1)
  k_aggregate<<<aggBlocks, 256, 0, stream>>>(Xhi, row_ptr, col_idx, invdeg,
                                             (unsigned int*)Mhi, (unsigned int*)Mlo, N);
  k_mfma_gemm<<<gemmBlocks, 256, 0, stream>>>(Mhi, Mlo, Xhi, Xlo, Wt[0], Wt[1], b1,
                                              Ahi, Alo, N);
  // layer 2: A -> X (h2)
  k_aggregate<<<aggBlocks, 256, 0, stream>>>(Ahi, row_ptr, col_idx, invdeg,
                                             (unsigned int*)Mhi, (unsigned int*)Mlo, N);
  k_mfma_gemm<<<gemmBlocks, 256, 0, stream>>>(Mhi, Mlo, Ahi, Alo, Wt[2], Wt[3], b2,
                                              Xhi, Xlo, N);
  // layer 3: X -> A (h3)
  k_aggregate<<<aggBlocks, 256, 0, stream>>>(Xhi, row_ptr, col_idx, invdeg,
                                             (unsigned int*)Mhi, (unsigned int*)Mlo, N);
  k_mfma_gemm<<<gemmBlocks, 256, 0, stream>>>(Mhi, Mlo, Xhi, Xlo, Wt[4], Wt[5], b3,
                                              Ahi, Alo, N);
  // final linear
  k_final<<<(N + 15) / 16, 256, 0, stream>>>(Ahi, Alo, Wlin, blin, out, N);
}

// Round 11
// 269.225 us; speedup vs baseline: 1.0566x; 1.0023x over previous
//
#include <hip/hip_runtime.h>

// ---------------------------------------------------------------------------
// 3-layer GraphSAGE (mean aggregation) + final linear.
// N=50000, 128 ch hidden, 800000 edges, out 16.
// R4: split-bf16 (hi/lo) MFMA GEMMs, K=256 combined; CSR de-atomic'd fill.
// R5/R6/R8 (REGRESSED, reverted). R7 best classic (276.6us).
// R10: GEMM kt-loop double-buffered (269.8us, best).
// R11: wide-gather aggregate k_agg4 (16B/lane, 4 rows/VMEM-inst, 16 rows in
//      flight; one end-of-node shfl reduce). A/B: layers 1+3 new, layer 2
//      classic anchor.
// ---------------------------------------------------------------------------

typedef short bf16x8 __attribute__((ext_vector_type(8)));  // 8 bf16 (4 VGPRs)
typedef float f32x4 __attribute__((ext_vector_type(4)));

__device__ __forceinline__ float bf16_to_f32(unsigned int lo16) {
  unsigned int u = lo16 << 16;
  return __builtin_bit_cast(float, u);
}
__device__ __forceinline__ unsigned short f32_to_bf16(float f) {
  unsigned int u = __builtin_bit_cast(unsigned int, f);
  unsigned int r = (u + 0x7FFFu + ((u >> 16) & 1u)) >> 16;  // RNE
  return (unsigned short)r;
}

// async global->LDS, 16B per lane; lds base must be wave-uniform.
__device__ __forceinline__ void gload_lds16(const void* g, void* lds_base) {
  __builtin_amdgcn_global_load_lds(
      (__attribute__((address_space(1))) unsigned int*)(uintptr_t)g,
      (__attribute__((address_space(3))) unsigned int*)(unsigned int)(uintptr_t)lds_base,
      16, 0, 0);
}

__global__ void k_zero_i32(int* __restrict__ p, int n) {
  int i = blockIdx.x * blockDim.x + threadIdx.x;
  if (i < n) p[i] = 0;
}

// fp32 -> bf16 hi/lo split, 4 elems/thread
__global__ __launch_bounds__(256) void k_split(const float* __restrict__ in,
                                               unsigned short* __restrict__ hi,
                                               unsigned short* __restrict__ lo, int n4) {
  int i = blockIdx.x * blockDim.x + threadIdx.x;
  if (i < n4) {
    float4 v = *reinterpret_cast<const float4*>(&in[(size_t)i * 4]);
    ushort4 h, l;
    h.x = f32_to_bf16(v.x); l.x = f32_to_bf16(v.x - bf16_to_f32(h.x));
    h.y = f32_to_bf16(v.y); l.y = f32_to_bf16(v.y - bf16_to_f32(h.y));
    h.z = f32_to_bf16(v.z); l.z = f32_to_bf16(v.z - bf16_to_f32(h.z));
    h.w = f32_to_bf16(v.w); l.w = f32_to_bf16(v.w - bf16_to_f32(h.w));
    *reinterpret_cast<ushort4*>(&hi[(size_t)i * 4]) = h;
    *reinterpret_cast<ushort4*>(&lo[(size_t)i * 4]) = l;
  }
}

// Weights: Wt[n][k] = (k<128 ? Wl[k][n] : Wr[k-128][n]), split hi/lo.
__global__ __launch_bounds__(256) void k_prep_w(const float* __restrict__ Wl,
                                                const float* __restrict__ Wr,
                                                unsigned short* __restrict__ Whi,
                                                unsigned short* __restrict__ Wlo) {
  int n = blockIdx.x, k = threadIdx.x;  // 128 blocks x 256 threads
  float v = (k < 128) ? Wl[(size_t)k * 128 + n] : Wr[(size_t)(k - 128) * 128 + n];
  unsigned short h = f32_to_bf16(v);
  Whi[(size_t)n * 256 + k] = h;
  Wlo[(size_t)n * 256 + k] = f32_to_bf16(v - bf16_to_f32(h));
}

// int32-vs-int64 edge_index detection
__global__ void k_detect(const int* __restrict__ ei, int* __restrict__ flag) {
  int t = threadIdx.x;
  int any = 0;
  for (int i = t; i < 1024; i += 256)
    if (ei[2 * i + 1] != 0) any = 1;
  if (any) atomicOr(flag, 1);
}

__device__ __forceinline__ int load_src(const int* ei, int E, int i, int is32) {
  return is32 ? ei[i] : ei[2 * i];
}
__device__ __forceinline__ int load_dst(const int* ei, int E, int i, int is32) {
  return is32 ? ei[E + i] : ei[2 * E + 2 * i];
}

// count degree + capture per-edge rank (removes atomic from k_fill)
__global__ __launch_bounds__(256) void k_count(const int* __restrict__ ei,
                                               const int* __restrict__ flag,
                                               int* __restrict__ deg,
                                               int* __restrict__ erank, int E) {
  int i = blockIdx.x * blockDim.x + threadIdx.x;
  if (i < E) {
    int is32 = *flag;
    erank[i] = atomicAdd(&deg[load_dst(ei, E, i, is32)], 1);
  }
}

// --- device-wide exclusive scan over deg (3 passes, 1024 elems/block) ------
__global__ __launch_bounds__(256) void k_scan1(const int* __restrict__ deg,
                                               int* __restrict__ bsum, int N) {
  __shared__ int s[256];
  int t = threadIdx.x;
  int base = blockIdx.x * 1024 + t * 4;
  int v = 0;
#pragma unroll
  for (int j = 0; j < 4; ++j) {
    int i = base + j;
    v += (i < N) ? deg[i] : 0;
  }
  s[t] = v;
  __syncthreads();
  for (int off = 128; off > 0; off >>= 1) {
    if (t < off) s[t] += s[t + off];
    __syncthreads();
  }
  if (t == 0) bsum[blockIdx.x] = s[0];
}

__global__ __launch_bounds__(1024) void k_scan2(int* __restrict__ bsum,
                                                int* __restrict__ row_ptr,
                                                int nb, int N) {
  __shared__ int s[1024];
  int t = threadIdx.x;
  int v = (t < nb) ? bsum[t] : 0;
  s[t] = v;
  __syncthreads();
  for (int off = 1; off < 1024; off <<= 1) {
    int add = (t >= off) ? s[t - off] : 0;
    __syncthreads();
    s[t] += add;
    __syncthreads();
  }
  if (t < nb) bsum[t] = s[t] - v;  // exclusive
  if (t == 1023) row_ptr[N] = s[1023];
}

__global__ __launch_bounds__(256) void k_scan3(const int* __restrict__ deg,
                                               const int* __restrict__ bsum,
                                               int* __restrict__ row_ptr,
                                               float* __restrict__ inv_deg, int N) {
  __shared__ int s[256];
  int t = threadIdx.x;
  int base = blockIdx.x * 1024 + t * 4;
  int v[4];
  int sum = 0;
#pragma unroll
  for (int j = 0; j < 4; ++j) {
    int i = base + j;
    v[j] = (i < N) ? deg[i] : 0;
    sum += v[j];
  }
  s[t] = sum;
  __syncthreads();
  for (int off = 1; off < 256; off <<= 1) {
    int add = (t >= off) ? s[t - off] : 0;
    __syncthreads();
    s[t] += add;
    __syncthreads();
  }
  int excl = s[t] - sum + bsum[blockIdx.x];
#pragma unroll
  for (int j = 0; j < 4; ++j) {
    int i = base + j;
    if (i < N) {
      row_ptr[i] = excl;
      inv_deg[i] = 1.0f / (float)((v[j] > 1) ? v[j] : 1);
      excl += v[j];
    }
  }
}

// pure scatter fill (rank precomputed)
__global__ __launch_bounds__(256) void k_fill(const int* __restrict__ ei,
                                              const int* __restrict__ flag,
                                              const int* __restrict__ row_ptr,
                                              const int* __restrict__ erank,
                                              int* __restrict__ col_idx, int E) {
  int i = blockIdx.x * blockDim.x + threadIdx.x;
  if (i < E) {
    int is32 = *flag;
    int d = load_dst(ei, E, i, is32);
    int s = load_src(ei, E, i, is32);
    col_idx[row_ptr[d] + erank[i]] = s;
  }
}

// Classic (R7) aggregate: one wave per node, 4B/lane, unroll-8. A/B anchor.
__global__ __launch_bounds__(256) void k_aggregate(const unsigned short* __restrict__ Xhi,
                                                   const int* __restrict__ row_ptr,
                                                   const int* __restrict__ col_idx,
                                                   const float* __restrict__ inv_deg,
                                                   unsigned int* __restrict__ Mhi,
                                                   unsigned int* __restrict__ Mlo, int N) {
  int gw = (int)((blockIdx.x * blockDim.x + threadIdx.x) >> 6);
  int lane = threadIdx.x & 63;
  if (gw >= N) return;
  int s = row_ptr[gw], e = row_ptr[gw + 1];
  const unsigned int* Xp =
      reinterpret_cast<const unsigned int*>(Xhi) + lane;  // row stride 64 u32
  float ax[8], ay[8];
#pragma unroll
  for (int q = 0; q < 8; ++q) { ax[q] = 0.f; ay[q] = 0.f; }
  int j = s;
  for (; j + 8 <= e; j += 8) {
    unsigned int v[8];
#pragma unroll
    for (int q = 0; q < 8; ++q) v[q] = Xp[(size_t)col_idx[j + q] * 64];
#pragma unroll
    for (int q = 0; q < 8; ++q) {
      ax[q] += bf16_to_f32(v[q] & 0xFFFFu);
      ay[q] += bf16_to_f32(v[q] >> 16);
    }
  }
  for (; j + 4 <= e; j += 4) {
    unsigned int v[4];
#pragma unroll
    for (int q = 0; q < 4; ++q) v[q] = Xp[(size_t)col_idx[j + q] * 64];
#pragma unroll
    for (int q = 0; q < 4; ++q) {
      ax[q] += bf16_to_f32(v[q] & 0xFFFFu);
      ay[q] += bf16_to_f32(v[q] >> 16);
    }
  }
  for (; j < e; ++j) {
    unsigned int v = Xp[(size_t)col_idx[j] * 64];
    ax[0] += bf16_to_f32(v & 0xFFFFu);
    ay[0] += bf16_to_f32(v >> 16);
  }
  float inv = inv_deg[gw];
  float rx = ((ax[0] + ax[1]) + (ax[2] + ax[3])) + ((ax[4] + ax[5]) + (ax[6] + ax[7]));
  float ry = ((ay[0] + ay[1]) + (ay[2] + ay[3])) + ((ay[4] + ay[5]) + (ay[6] + ay[7]));
  rx *= inv;
  ry *= inv;
  unsigned int hx = f32_to_bf16(rx), hy = f32_to_bf16(ry);
  unsigned int lx = f32_to_bf16(rx - bf16_to_f32(hx));
  unsigned int ly = f32_to_bf16(ry - bf16_to_f32(hy));
  Mhi[(size_t)gw * 64 + lane] = hx | (hy << 16);
  Mlo[(size_t)gw * 64 + lane] = lx | (ly << 16);
}

// Wide-gather aggregate: wave = 4 groups x 16 lanes; group g loads neighbor
// rows s+g, s+g+4, ... as uint4 (16B/lane x 16 lanes = 256B row). 4 rows per
// VMEM inst, unroll-4 = 16 rows in flight. One shfl-reduce per node at end;
// groups 0/1 store packed hi/lo uint4 (coalesced).
__global__ __launch_bounds__(256) void k_agg4(const unsigned short* __restrict__ Xhi,
                                              const int* __restrict__ row_ptr,
                                              const int* __restrict__ col_idx,
                                              const float* __restrict__ inv_deg,
                                              uint4* __restrict__ Mhi,
                                              uint4* __restrict__ Mlo, int N) {
  int gw = (int)((blockIdx.x * blockDim.x + threadIdx.x) >> 6);
  int lane = threadIdx.x & 63;
  if (gw >= N) return;
  int g = lane >> 4, sl = lane & 15;
  int s = row_ptr[gw], e = row_ptr[gw + 1];
  const uint4* X4 = reinterpret_cast<const uint4*>(Xhi);  // row = 16 uint4
  float acc[8];
#pragma unroll
  for (int k = 0; k < 8; ++k) acc[k] = 0.f;

  auto addv = [&](uint4 v) {
    acc[0] += bf16_to_f32(v.x & 0xFFFFu);
    acc[1] += bf16_to_f32(v.x >> 16);
    acc[2] += bf16_to_f32(v.y & 0xFFFFu);
    acc[3] += bf16_to_f32(v.y >> 16);
    acc[4] += bf16_to_f32(v.z & 0xFFFFu);
    acc[5] += bf16_to_f32(v.z >> 16);
    acc[6] += bf16_to_f32(v.w & 0xFFFFu);
    acc[7] += bf16_to_f32(v.w >> 16);
  };

  int j = s + g;
  for (; j + 12 < e; j += 16) {  // 4 stride-4 elems of this group's stream
    uint4 v0 = X4[(size_t)col_idx[j] * 16 + sl];
    uint4 v1 = X4[(size_t)col_idx[j + 4] * 16 + sl];
    uint4 v2 = X4[(size_t)col_idx[j + 8] * 16 + sl];
    uint4 v3 = X4[(size_t)col_idx[j + 12] * 16 + sl];
    addv(v0);
    addv(v1);
    addv(v2);
    addv(v3);
  }
  for (; j < e; j += 4) {
    uint4 v = X4[(size_t)col_idx[j] * 16 + sl];
    addv(v);
  }

  float inv = inv_deg[gw];
#pragma unroll
  for (int k = 0; k < 8; ++k) {
    float v = acc[k];
    v += __shfl_xor(v, 16, 64);
    v += __shfl_xor(v, 32, 64);
    acc[k] = v * inv;
  }
  if (g < 2) {
    unsigned int h[4], l[4];
#pragma unroll
    for (int k = 0; k < 4; ++k) {
      unsigned int h0 = f32_to_bf16(acc[2 * k]);
      unsigned int h1 = f32_to_bf16(acc[2 * k + 1]);
      h[k] = h0 | (h1 << 16);
      unsigned int l0 = f32_to_bf16(acc[2 * k] - bf16_to_f32(h0));
      unsigned int l1 = f32_to_bf16(acc[2 * k + 1] - bf16_to_f32(h1));
      l[k] = l0 | (l1 << 16);
    }
    if (g == 0)
      Mhi[(size_t)gw * 16 + sl] = make_uint4(h[0], h[1], h[2], h[3]);
    else
      Mlo[(size_t)gw * 16 + sl] = make_uint4(l[0], l[1], l[2], l[3]);
  }
}

// MFMA GEMM: Out = relu([A1 | A2](N x 256) @ Wt^T + bias), split-bf16 3-pass.
// Block: 128 rows x 128 cols, 4 waves (2x2), wave = 64x64 via 4x4 16x16x32.
// Double-buffered kt-loop (R10).
__global__ __launch_bounds__(256) void k_mfma_gemm(
    const unsigned short* __restrict__ A1hi, const unsigned short* __restrict__ A1lo,
    const unsigned short* __restrict__ A2hi, const unsigned short* __restrict__ A2lo,
    const unsigned short* __restrict__ Whi, const unsigned short* __restrict__ Wlo,
    const float* __restrict__ bias,
    unsigned short* __restrict__ Ohi, unsigned short* __restrict__ Olo, int N) {
  __shared__ unsigned short sAhi[2][128 * 32], sAlo[2][128 * 32];
  __shared__ unsigned short sBhi[2][128 * 32], sBlo[2][128 * 32];
  int t = threadIdx.x;
  int lane = t & 63;
  int w = t >> 6;
  int wr = (w >> 1) * 64, wc = (w & 1) * 64;
  int block_row = blockIdx.x * 128;

  f32x4 acc[4][4];
#pragma unroll
  for (int m = 0; m < 4; ++m)
#pragma unroll
    for (int n = 0; n < 4; ++n) acc[m][n] = f32x4{0.f, 0.f, 0.f, 0.f};

  int kg = lane & 3;           // 16B group within 64B row
  int rr = lane >> 2;          // 0..15 row-within-chunk
  int fr = lane & 15;          // fragment row/col
  int fkb = (lane >> 4) * 16;  // fragment k byte offset

  auto stage = [&](int kt, int b) {
    const unsigned short* gsrc;
    unsigned short* lbase;
    int isA = (w < 2);
    if (w == 0) { gsrc = (kt < 4) ? A1hi : A2hi; lbase = sAhi[b]; }
    else if (w == 1) { gsrc = (kt < 4) ? A1lo : A2lo; lbase = sAlo[b]; }
    else if (w == 2) { gsrc = Whi; lbase = sBhi[b]; }
    else { gsrc = Wlo; lbase = sBlo[b]; }
#pragma unroll
    for (int c = 0; c < 8; ++c) {
      int idx = c * 16 + rr;  // A: row; B: col
      const char* src;
      if (isA) {
        int rg = block_row + idx;
        if (rg > N - 1) rg = N - 1;
        src = (const char*)gsrc + (size_t)rg * 256 + (kt & 3) * 64 + kg * 16;
      } else {
        src = (const char*)gsrc + (size_t)idx * 512 + kt * 64 + kg * 16;
      }
      gload_lds16(src, (char*)lbase + c * 1024);
    }
  };

  stage(0, 0);
  __syncthreads();

  for (int kt = 0; kt < 8; ++kt) {
    int cur = kt & 1;
    if (kt < 7) stage(kt + 1, cur ^ 1);
    bf16x8 a_hi[4], a_lo[4], b_hi[4], b_lo[4];
#pragma unroll
    for (int m = 0; m < 4; ++m) {
      int row = wr + m * 16 + fr;
      a_hi[m] = *reinterpret_cast<const bf16x8*>((const char*)sAhi[cur] + row * 64 + fkb);
      a_lo[m] = *reinterpret_cast<const bf16x8*>((const char*)sAlo[cur] + row * 64 + fkb);
    }
#pragma unroll
    for (int n = 0; n < 4; ++n) {
      int col = wc + n * 16 + fr;
      b_hi[n] = *reinterpret_cast<const bf16x8*>((const char*)sBhi[cur] + col * 64 + fkb);
      b_lo[n] = *reinterpret_cast<const bf16x8*>((const char*)sBlo[cur] + col * 64 + fkb);
    }
#pragma unroll
    for (int m = 0; m < 4; ++m)
#pragma unroll
      for (int n = 0; n < 4; ++n) {
        acc[m][n] = __builtin_amdgcn_mfma_f32_16x16x32_bf16(a_hi[m], b_hi[n], acc[m][n], 0, 0, 0);
        acc[m][n] = __builtin_amdgcn_mfma_f32_16x16x32_bf16(a_hi[m], b_lo[n], acc[m][n], 0, 0, 0);
        acc[m][n] = __builtin_amdgcn_mfma_f32_16x16x32_bf16(a_lo[m], b_hi[n], acc[m][n], 0, 0, 0);
      }
    __syncthreads();
  }

  float bv[4];
#pragma unroll
  for (int n = 0; n < 4; ++n) bv[n] = bias[wc + n * 16 + (lane & 15)];
#pragma unroll
  for (int m = 0; m < 4; ++m) {
#pragma unroll
    for (int n = 0; n < 4; ++n) {
#pragma unroll
      for (int j = 0; j < 4; ++j) {
        int row_l = wr + m * 16 + (lane >> 4) * 4 + j;
        int g = block_row + row_l;
        if (g < N) {
          int col = wc + n * 16 + (lane & 15);
          float v = fmaxf(acc[m][n][j] + bv[n], 0.f);
          unsigned short h = f32_to_bf16(v);
          Ohi[(size_t)g * 128 + col] = h;
          Olo[(size_t)g * 128 + col] = f32_to_bf16(v - bf16_to_f32(h));
        }
      }
    }
  }
}

// Final: Out[N][16] = H[N][128] @ W[128][16] + b; H reconstructed from hi+lo.
__global__ __launch_bounds__(256) void k_final(const unsigned short* __restrict__ Hhi,
                                               const unsigned short* __restrict__ Hlo,
                                               const float* __restrict__ W,
                                               const float* __restrict__ b,
                                               float* __restrict__ Out, int N) {
  __shared__ float sH[16][128];
  __shared__ float sW[128][16];
  __shared__ float sb[16];
  int t = threadIdx.x;
  int node0 = blockIdx.x * 16;
  {
    int row = t >> 4, q = t & 15;  // 8 elems each
    int g = node0 + row;
    if (g < N) {
      uint4 hv = *reinterpret_cast<const uint4*>(&Hhi[(size_t)g * 128 + q * 8]);
      uint4 lv = *reinterpret_cast<const uint4*>(&Hlo[(size_t)g * 128 + q * 8]);
      const unsigned short* hp = (const unsigned short*)&hv;
      const unsigned short* lp = (const unsigned short*)&lv;
#pragma unroll
      for (int e = 0; e < 8; ++e)
        sH[row][q * 8 + e] = bf16_to_f32(hp[e]) + bf16_to_f32(lp[e]);
    } else {
#pragma unroll
      for (int e = 0; e < 8; ++e) sH[row][q * 8 + e] = 0.f;
    }
  }
  for (int j = t; j < 512; j += 256) {
    int row = j >> 2, q = j & 3;
    *reinterpret_cast<float4*>(&sW[row][q * 4]) =
        *reinterpret_cast<const float4*>(&W[(size_t)row * 16 + q * 4]);
  }
  if (t < 16) sb[t] = b[t];
  __syncthreads();
  int node = t >> 4, col = t & 15;
  float acc = sb[col];
#pragma unroll 8
  for (int k = 0; k < 128; ++k) acc = fmaf(sH[node][k], sW[k][col], acc);
  int g = node0 + node;
  if (g < N) Out[(size_t)g * 16 + col] = acc;
}

extern "C" void kernel_launch(void* const* d_in, const int* in_sizes, int n_in,
                              void* d_out, int out_size, void* d_ws, size_t ws_size,
                              hipStream_t stream) {
  if (n_in < 13) return;
  const float* x = (const float*)d_in[0];
  const int* ei = (const int*)d_in[1];
  const float* W1l = (const float*)d_in[2];
  const float* b1 = (const float*)d_in[3];
  const float* W1r = (const float*)d_in[4];
  const float* W2l = (const float*)d_in[5];
  const float* b2 = (const float*)d_in[6];
  const float* W2r = (const float*)d_in[7];
  const float* W3l = (const float*)d_in[8];
  const float* b3 = (const float*)d_in[9];
  const float* W3r = (const float*)d_in[10];
  const float* Wlin = (const float*)d_in[11];
  const float* blin = (const float*)d_in[12];
  float* out = (float*)d_out;

  const int N = in_sizes[0] / 128;
  const int E = in_sizes[1] / 2;

  char* w = (char*)d_ws;
  size_t off = 0;
  auto alloc = [&](size_t bytes) -> void* {
    off = (off + 255) & ~(size_t)255;
    void* p = (void*)(w + off);
    off += bytes;
    return p;
  };
  size_t actB = (size_t)N * 128 * 2;
  unsigned short* Xhi = (unsigned short*)alloc(actB);
  unsigned short* Xlo = (unsigned short*)alloc(actB);
  unsigned short* Ahi = (unsigned short*)alloc(actB);
  unsigned short* Alo = (unsigned short*)alloc(actB);
  unsigned short* Mhi = (unsigned short*)alloc(actB);
  unsigned short* Mlo = (unsigned short*)alloc(actB);
  unsigned short* Wt[6];
  for (int i = 0; i < 6; ++i) Wt[i] = (unsigned short*)alloc(128 * 256 * 2);
  int* deg = (int*)alloc((size_t)N * 4);
  int* row_ptr = (int*)alloc((size_t)(N + 1) * 4);
  int* col_idx = (int*)alloc((size_t)E * 4);
  int* erank = (int*)alloc((size_t)E * 4);
  float* invdeg = (float*)alloc((size_t)N * 4);
  int* flag = (int*)alloc(4);
  int* bsum = (int*)alloc((size_t)1024 * 4);
  (void)ws_size;

  const int nbScan = (N + 1023) / 1024;

  // CSR build + operand prep
  k_zero_i32<<<(N + 255) / 256, 256, 0, stream>>>(deg, N);
  k_zero_i32<<<1, 256, 0, stream>>>(flag, 1);
  k_detect<<<1, 256, 0, stream>>>(ei, flag);
  k_count<<<(E + 255) / 256, 256, 0, stream>>>(ei, flag, deg, erank, E);
  k_split<<<(N * 32 + 255) / 256, 256, 0, stream>>>(x, Xhi, Xlo, N * 32);
  k_prep_w<<<128, 256, 0, stream>>>(W1l, W1r, Wt[0], Wt[1]);
  k_prep_w<<<128, 256, 0, stream>>>(W2l, W2r, Wt[2], Wt[3]);
  k_prep_w<<<128, 256, 0, stream>>>(W3l, W3r, Wt[4], Wt[5]);
  k_scan1<<<nbScan, 256, 0, stream>>>(deg, bsum, N);
  k_scan2<<<1, 1024, 0, stream>>>(bsum, row_ptr, nbScan, N);
  k_scan3<<<nbScan, 256, 0, stream>>>(deg, bsum, row_ptr, invdeg, N);
  k_fill<<<(E + 255) / 256, 256, 0, stream>>>(ei, flag, row_ptr, erank, col_idx, E);

  int aggBlocks = (N * 64 + 255) / 256;
  int gemmBlocks = (N + 127) / 128;

  // layer 1: X -> A (h1)  [wide-gather]
  k_agg4<<<aggBlocks, 256, 0, stream>>>(Xhi, row_ptr, col_idx, invdeg,
                                        (uint4*)Mhi, (uint4*)Mlo, N);
  k_mfma_gemm<<<gemmBlocks, 256, 0, stream>>>(Mhi, Mlo, Xhi, Xlo, Wt[0], Wt[1], b1,
                                              Ahi, Alo, N);
  // layer 2: A -> X (h2)  [classic anchor]
  k_aggregate<<<aggBlocks, 256, 0, stream>>>(Ahi, row_ptr, col_idx, invdeg,
                                             (unsigned int*)Mhi, (unsigned int*)Mlo, N);
  k_mfma_gemm<<<gemmBlocks, 256, 0, stream>>>(Mhi, Mlo, Ahi, Alo, Wt[2], Wt[3], b2,
                                              Xhi, Xlo, N);
  // layer 3: X -> A (h3)  [wide-gather]
  k_agg4<<<aggBlocks, 256, 0, stream>>>(Xhi, row_ptr, col_idx, invdeg,
                                        (uint4*)Mhi, (uint4*)Mlo, N);
  k_mfma_gemm<<<gemmBlocks, 256, 0, stream>>>(Mhi, Mlo, Xhi, Xlo, Wt[4], Wt[5], b3,
                                              Ahi, Alo, N);
  // final linear
  k_final<<<(N + 15) / 16, 256, 0, stream>>>(Ahi, Alo, Wlin, blin, out, N);
}